// Round 7
// baseline (424.935 us; speedup 1.0000x reference)
//
#include <hip/hip_runtime.h>
#include <hip/hip_bf16.h>
#include <math.h>

#define Bn 2
#define Cn 256
#define Nn 13824
#define NHn 4
#define Pn 64
#define Gn 8
#define NCH 54      // Nn/256

typedef __bf16 bf16x8 __attribute__((ext_vector_type(8)));
typedef unsigned short us8v __attribute__((ext_vector_type(8)));
typedef unsigned short us4v __attribute__((ext_vector_type(4)));
typedef float f32x4 __attribute__((ext_vector_type(4)));

__device__ __forceinline__ unsigned short f2bf(float f) {
  __hip_bfloat16 h = __float2bfloat16(f);
  return __builtin_bit_cast(unsigned short, h);
}
__device__ __forceinline__ float bf2f(unsigned short u) {
  return __builtin_bit_cast(float, ((unsigned)u) << 16);
}
__device__ __forceinline__ unsigned pk2(float a, float b) {
  return (unsigned)f2bf(a) | ((unsigned)f2bf(b) << 16);
}

// ================= prep: zeros, x->xT bf16, weight expands/transposes ========
// regions: [0]=zeros, [1..1728]=xT, [+512]=Wexpand, [+48]=wqkvT, [+16]=w1T/w2T,
//          [+216]=weT.   total 2521 blocks
__global__ __launch_bounds__(256) void k_prep(
    const float* __restrict__ x, const float* __restrict__ wqkv,
    const float* __restrict__ w_e, const float* __restrict__ w1,
    const float* __restrict__ w2, const float* __restrict__ wc1,
    const float* __restrict__ wc2,
    unsigned short* __restrict__ xTbf, unsigned short* __restrict__ W1e,
    unsigned short* __restrict__ W2e, unsigned short* __restrict__ wqkvT,
    unsigned short* __restrict__ w1T, unsigned short* __restrict__ w2T,
    unsigned short* __restrict__ weT, float* __restrict__ zeros) {
  __shared__ float tl[64][65];
  int bid = blockIdx.x, t = threadIdx.x;
  if (bid == 0) {
    #pragma unroll
    for (int i = 0; i < 12; i++) zeros[t + i * 256] = 0.f;
    return;
  }
  bid -= 1;
  if (bid < 1728) {           // x transpose -> bf16 [b][n][c]
    int b = bid / 864, rem = bid % 864;
    int c0 = (rem / 216) * 64, n0 = (rem % 216) * 64;
    int nc = t & 63, cr = t >> 6;
    #pragma unroll
    for (int k = 0; k < 16; k++)
      tl[cr + k * 4][nc] = x[((size_t)b * Cn + c0 + cr + k * 4) * Nn + n0 + nc];
    __syncthreads();
    int nrow = t >> 2, cs = (t & 3) * 16;
    us8v o0, o1;
    #pragma unroll
    for (int i = 0; i < 8; i++) {
      o0[i] = f2bf(tl[cs + i][nrow]);
      o1[i] = f2bf(tl[cs + 8 + i][nrow]);
    }
    unsigned short* dp = xTbf + ((size_t)b * Nn + n0 + nrow) * 256 + c0 + cs;
    *(us8v*)dp = o0; *(us8v*)(dp + 8) = o1;
    return;
  }
  bid -= 1728;
  if (bid < 512) {            // block-diag W expand [cout][cin] bf16
    int cv = bid >> 8, cout = bid & 255, cin = t;
    const float* w = cv ? wc2 : wc1;
    unsigned short* We = cv ? W2e : W1e;
    float val = ((cout >> 5) == (cin >> 5))
                    ? w[(cout >> 5) * 1024 + (cin & 31) * 32 + (cout & 31)] : 0.f;
    We[cout * 256 + cin] = f2bf(val);
    return;
  }
  bid -= 512;
  if (bid < 48) {             // wqkvT [768 j][256 c]
    int j0 = (bid / 4) * 64, c0 = (bid & 3) * 64;
    int jc = t & 63, cr = t >> 6;
    #pragma unroll
    for (int k = 0; k < 16; k++)
      tl[cr + k * 4][jc] = wqkv[(size_t)(c0 + cr + k * 4) * 768 + j0 + jc];
    __syncthreads();
    int jrow = t >> 2, cs = (t & 3) * 16;
    us8v o0, o1;
    #pragma unroll
    for (int i = 0; i < 8; i++) {
      o0[i] = f2bf(tl[cs + i][jrow]);
      o1[i] = f2bf(tl[cs + 8 + i][jrow]);
    }
    unsigned short* dp = wqkvT + (size_t)(j0 + jrow) * 256 + c0 + cs;
    *(us8v*)dp = o0; *(us8v*)(dp + 8) = o1;
    return;
  }
  bid -= 48;
  if (bid < 16) {             // w1T/w2T [128 j][256 c]
    int mat = bid >> 3, rem = bid & 7;
    int j0 = (rem >> 2) * 64, c0 = (rem & 3) * 64;
    const float* src = mat ? w2 : w1;
    unsigned short* dstw = mat ? w2T : w1T;
    int jc = t & 63, cr = t >> 6;
    #pragma unroll
    for (int k = 0; k < 16; k++)
      tl[cr + k * 4][jc] = src[(size_t)(c0 + cr + k * 4) * 128 + j0 + jc];
    __syncthreads();
    int jrow = t >> 2, cs = (t & 3) * 16;
    us8v o0, o1;
    #pragma unroll
    for (int i = 0; i < 8; i++) {
      o0[i] = f2bf(tl[cs + i][jrow]);
      o1[i] = f2bf(tl[cs + 8 + i][jrow]);
    }
    unsigned short* dp = dstw + (size_t)(j0 + jrow) * 256 + c0 + cs;
    *(us8v*)dp = o0; *(us8v*)(dp + 8) = o1;
    return;
  }
  bid -= 16;
  {                           // weT [64 p][Nn]
    int n0 = bid * 64;
    int p = t & 63, nr = t >> 6;
    #pragma unroll
    for (int k = 0; k < 16; k++)
      tl[nr + k * 4][p] = w_e[(size_t)(n0 + nr + k * 4) * 64 + p];
    __syncthreads();
    int prow = t >> 2, ns = (t & 3) * 16;
    us8v o0, o1;
    #pragma unroll
    for (int i = 0; i < 8; i++) {
      o0[i] = f2bf(tl[ns + i][prow]);
      o1[i] = f2bf(tl[ns + 8 + i][prow]);
    }
    unsigned short* dp = weT + (size_t)prow * Nn + n0 + ns;
    *(us8v*)dp = o0; *(us8v*)(dp + 8) = o1;
  }
}

// ============ unified MFMA GEMM: C[n][j] = B[n][c] x A[j][c]^T ===============
// MODE 0: conv1 (bias + stat sums)   MODE 1: conv2 (inorm+lrelu on B, bias+stats)
// MODE 2: q GEMM (qsq sums only)
template <int MODE>
__global__ __launch_bounds__(256) void k_mm(
    const unsigned short* __restrict__ Aw, const unsigned short* __restrict__ Bx,
    const float* __restrict__ bias, const float* __restrict__ instats,
    unsigned short* __restrict__ dst, float* __restrict__ statacc) {
  __shared__ char lds[36864];
  int b = blockIdx.z, n0 = blockIdx.x * 128, j0 = blockIdx.y * 128;
  int t = threadIdx.x, lane = t & 63, wid = t >> 6;
  int wj = wid >> 1, wt = wid & 1;
  float* bias_s = (float*)(lds + 33792);
  float* ms = (float*)(lds + 34304);
  float* rs = (float*)(lds + 35328);
  if (MODE != 2 && t < 128) bias_s[t] = bias[j0 + t];
  if (MODE == 1) {
    ms[t] = instats[(b * Cn + t) * 2 + 0];
    rs[t] = instats[(b * Cn + t) * 2 + 1];
  }
  __syncthreads();
  f32x4 acc[4][4];
  #pragma unroll
  for (int i = 0; i < 4; i++)
    #pragma unroll
    for (int j = 0; j < 4; j++) acc[i][j] = (f32x4){0.f, 0.f, 0.f, 0.f};
  int r = t >> 1, off = (t & 1) * 32;
  for (int k0 = 0; k0 < 256; k0 += 64) {
    const unsigned short* ga = Aw + (size_t)(j0 + r) * 256 + k0 + off;
    const unsigned short* gb = Bx + ((size_t)b * Nn + n0 + r) * 256 + k0 + off;
    #pragma unroll
    for (int i = 0; i < 4; i++) {
      *(us8v*)(lds + r * 128 + ((off * 2 + 16 * i) ^ ((r & 7) << 4))) = *(const us8v*)(ga + i * 8);
      us8v v = *(const us8v*)(gb + i * 8);
      if (MODE == 1) {
        #pragma unroll
        for (int e = 0; e < 8; e++) {
          int c = k0 + off + i * 8 + e;
          float f = (bf2f(v[e]) - ms[c]) * rs[c];
          f = f >= 0.f ? f : 0.01f * f;
          v[e] = f2bf(f);
        }
      }
      *(us8v*)(lds + 16384 + r * 128 + ((off * 2 + 16 * i) ^ ((r & 7) << 4))) = v;
    }
    __syncthreads();
    #pragma unroll
    for (int ks = 0; ks < 2; ks++) {
      int kb = ks * 64 + (lane >> 4) * 16;
      bf16x8 af[4], bfr[4];
      #pragma unroll
      for (int mt = 0; mt < 4; mt++) {
        int row = wj * 64 + mt * 16 + (lane & 15);
        af[mt] = *(bf16x8*)(lds + row * 128 + (kb ^ ((row & 7) << 4)));
      }
      #pragma unroll
      for (int tt = 0; tt < 4; tt++) {
        int row = wt * 64 + tt * 16 + (lane & 15);
        bfr[tt] = *(bf16x8*)(lds + 16384 + row * 128 + (kb ^ ((row & 7) << 4)));
      }
      #pragma unroll
      for (int mt = 0; mt < 4; mt++)
        #pragma unroll
        for (int tt = 0; tt < 4; tt++)
          acc[mt][tt] = __builtin_amdgcn_mfma_f32_16x16x32_bf16(af[mt], bfr[tt], acc[mt][tt], 0, 0, 0);
    }
    __syncthreads();
  }
  if (MODE != 2) {
    #pragma unroll
    for (int mt = 0; mt < 4; mt++)
      #pragma unroll
      for (int tt = 0; tt < 4; tt++)
        #pragma unroll
        for (int e = 0; e < 4; e++)
          acc[mt][tt][e] += bias_s[wj * 64 + mt * 16 + (lane >> 4) * 4 + e];
    #pragma unroll
    for (int mt = 0; mt < 4; mt++)
      #pragma unroll
      for (int e = 0; e < 4; e++) {
        float s = 0.f, ss = 0.f;
        #pragma unroll
        for (int tt = 0; tt < 4; tt++) {
          float v = acc[mt][tt][e];
          s += v; ss = fmaf(v, v, ss);
        }
        #pragma unroll
        for (int m = 1; m < 16; m <<= 1) { s += __shfl_xor(s, m); ss += __shfl_xor(ss, m); }
        if ((lane & 15) == 0) {
          int c = b * Cn + j0 + wj * 64 + mt * 16 + (lane >> 4) * 4 + e;
          atomicAdd(&statacc[c * 2 + 0], s);
          atomicAdd(&statacc[c * 2 + 1], ss);
        }
      }
  } else {
    #pragma unroll
    for (int mt = 0; mt < 4; mt++)
      #pragma unroll
      for (int e = 0; e < 4; e++) {
        float ss = 0.f;
        #pragma unroll
        for (int tt = 0; tt < 4; tt++) { float v = acc[mt][tt][e]; ss = fmaf(v, v, ss); }
        #pragma unroll
        for (int m = 1; m < 16; m <<= 1) ss += __shfl_xor(ss, m);
        if ((lane & 15) == 0)
          atomicAdd(&statacc[b * Cn + j0 + wj * 64 + mt * 16 + (lane >> 4) * 4 + e], ss);
      }
  }
  unsigned short* O = (unsigned short*)lds;  // [128][132]
  #pragma unroll
  for (int mt = 0; mt < 4; mt++)
    #pragma unroll
    for (int tt = 0; tt < 4; tt++) {
      int tok = wt * 64 + tt * 16 + (lane & 15);
      int jb = wj * 64 + mt * 16 + (lane >> 4) * 4;
      uint2 v;
      v.x = pk2(acc[mt][tt][0], acc[mt][tt][1]);
      v.y = pk2(acc[mt][tt][2], acc[mt][tt][3]);
      *(uint2*)(O + tok * 132 + jb) = v;
    }
  __syncthreads();
  int tok = t >> 1, js = (t & 1) * 64;
  unsigned short* dp = dst + ((size_t)b * Nn + n0 + tok) * 256 + j0 + js;
  #pragma unroll
  for (int i = 0; i < 8; i++) *(us8v*)(dp + i * 8) = *(const us8v*)(O + tok * 132 + js + i * 8);
}

// ---------------- stats finalize: sums -> mean/rstd ----------------
__global__ __launch_bounds__(256) void k_statfin(const float* __restrict__ acc,
                                                 float* __restrict__ stats) {
  int r = blockIdx.x * 256 + threadIdx.x;
  float s = acc[r * 2], ss = acc[r * 2 + 1];
  float m = s * (1.f / Nn);
  float var = ss * (1.f / Nn) - m * m;
  stats[r * 2 + 0] = m;
  stats[r * 2 + 1] = rsqrtf(var + 1e-5f);
}

// ====== fused resid + token-LN both paths, token-major, single pass =========
__global__ __launch_bounds__(256) void k_fused_ln(
    const unsigned short* __restrict__ xT, const unsigned short* __restrict__ t3T,
    const float* __restrict__ pos, const float* __restrict__ stats3,
    const float* __restrict__ g, const float* __restrict__ beta,
    const float* __restrict__ wpool,
    unsigned short* __restrict__ xnbf, unsigned short* __restrict__ xcnbf,
    float* __restrict__ pooledacc) {
  int b = blockIdx.y, n0 = blockIdx.x * 32;
  int t = threadIdx.x;
  int tokid = t >> 3, cseg = t & 7;          // token n0+tokid, channels cseg*32..
  __shared__ float s3m[256], s3r[256], gb[256], bb[256];
  __shared__ float pred[4][8][32];
  s3m[t] = stats3[(b * Cn + t) * 2 + 0];
  s3r[t] = stats3[(b * Cn + t) * 2 + 1];
  gb[t] = g[t]; bb[t] = beta[t];
  __syncthreads();
  int n = n0 + tokid;
  size_t rowb = ((size_t)b * Nn + n) * 256 + cseg * 32;
  size_t rowp = (size_t)n * 256 + cseg * 32;
  float v1[32], v2[32];
  float s1 = 0.f, q1 = 0.f, s2 = 0.f, q2 = 0.f;
  #pragma unroll
  for (int i = 0; i < 4; i++) {
    us8v x8 = *(const us8v*)(xT + rowb + i * 8);
    us8v t8 = *(const us8v*)(t3T + rowb + i * 8);
    f32x4 pa = *(const f32x4*)(pos + rowp + i * 8);
    f32x4 pb = *(const f32x4*)(pos + rowp + i * 8 + 4);
    #pragma unroll
    for (int j = 0; j < 8; j++) {
      int c = cseg * 32 + i * 8 + j;
      float xv = bf2f(x8[j]);
      float pv = j < 4 ? pa[j] : pb[j - 4];
      float a = xv + pv;
      v1[i * 8 + j] = a;
      s1 += a; q1 = fmaf(a, a, q1);
      float xc = (bf2f(t8[j]) - s3m[c]) * s3r[c] + xv;
      xc = xc >= 0.f ? xc : 0.01f * xc;
      float d = xc + pv;
      v2[i * 8 + j] = d;
      s2 += d; q2 = fmaf(d, d, q2);
    }
  }
  #pragma unroll
  for (int m = 1; m < 8; m <<= 1) {
    s1 += __shfl_xor(s1, m); q1 += __shfl_xor(q1, m);
    s2 += __shfl_xor(s2, m); q2 += __shfl_xor(q2, m);
  }
  float m1 = s1 * (1.f / 256.f);
  float r1 = rsqrtf(q1 * (1.f / 256.f) - m1 * m1 + 1e-5f);
  float m2 = s2 * (1.f / 256.f);
  float r2 = rsqrtf(q2 * (1.f / 256.f) - m2 * m2 + 1e-5f);
  float wpl = wpool[n];
  float pp[32];
  #pragma unroll
  for (int i = 0; i < 4; i++) {
    us8v o1, o2;
    #pragma unroll
    for (int j = 0; j < 8; j++) {
      int c = cseg * 32 + i * 8 + j;
      o1[j] = f2bf((v1[i * 8 + j] - m1) * r1 * gb[c] + bb[c]);
      float oc = (v2[i * 8 + j] - m2) * r2 * gb[c] + bb[c];
      o2[j] = f2bf(oc);
      pp[i * 8 + j] = oc * wpl;
    }
    *(us8v*)(xnbf + rowb + i * 8) = o1;
    *(us8v*)(xcnbf + rowb + i * 8) = o2;
  }
  // pooled: reduce over 8 tokens of this wave per channel slot
  #pragma unroll
  for (int i = 0; i < 32; i++) {
    pp[i] += __shfl_xor(pp[i], 8);
    pp[i] += __shfl_xor(pp[i], 16);
    pp[i] += __shfl_xor(pp[i], 32);
  }
  int w = t >> 6;
  if ((t & 63) < 8) {
    #pragma unroll
    for (int i = 0; i < 32; i++) pred[w][t & 7][i] = pp[i];
  }
  __syncthreads();
  float psum = pred[0][t >> 5][t & 31] + pred[1][t >> 5][t & 31] +
               pred[2][t >> 5][t & 31] + pred[3][t >> 5][t & 31];
  atomicAdd(&pooledacc[b * Cn + t], psum);
}

// ---------------- bf16 transpose [b][n][c] -> [b][c][n] ----------------
__global__ __launch_bounds__(256) void k_xpose(const unsigned short* __restrict__ src,
                                               unsigned short* __restrict__ dstT) {
  __shared__ unsigned tile[64][33];
  int n0 = blockIdx.x * 64, c0 = blockIdx.y * 64, b = blockIdx.z;
  int t = threadIdx.x;
  int nr = t >> 2, cs = (t & 3) * 16;
  const unsigned short* sp = src + ((size_t)b * Nn + n0 + nr) * 256 + c0 + cs;
  us8v v0 = *(const us8v*)sp;
  us8v v1 = *(const us8v*)(sp + 8);
  unsigned* tp = &tile[nr][cs >> 1];
  #pragma unroll
  for (int i = 0; i < 4; i++) tp[i] = (unsigned)v0[2 * i] | ((unsigned)v0[2 * i + 1] << 16);
  #pragma unroll
  for (int i = 0; i < 4; i++) tp[4 + i] = (unsigned)v1[2 * i] | ((unsigned)v1[2 * i + 1] << 16);
  __syncthreads();
  int crow = t >> 2, ns = (t & 3) * 16;
  int c2 = crow >> 1, sel = (crow & 1) * 16;
  us8v o0, o1;
  #pragma unroll
  for (int i = 0; i < 8; i++) {
    o0[i] = (unsigned short)(tile[ns + i][c2] >> sel);
    o1[i] = (unsigned short)(tile[ns + 8 + i][c2] >> sel);
  }
  unsigned short* dp = dstT + ((size_t)b * Cn + c0 + crow) * Nn + n0 + ns;
  *(us8v*)dp = o0; *(us8v*)(dp + 8) = o1;
}

// ---------------- xe (bf16 MFMA split-K): part[b,ch][c][p] ----------------
__global__ __launch_bounds__(256) void k_xe(const unsigned short* __restrict__ xnT,
                                            const unsigned short* __restrict__ weT,
                                            float* __restrict__ part) {
  __shared__ char lds[16384];
  int chunk = blockIdx.x, ct = blockIdx.y, b = blockIdx.z;
  int c0 = ct * 64, nb = chunk * 256;
  int t = threadIdx.x, lane = t & 63, wid = t >> 6;
  f32x4 acc4[4];
  #pragma unroll
  for (int i = 0; i < 4; i++) acc4[i] = (f32x4){0.f, 0.f, 0.f, 0.f};
  for (int k0 = 0; k0 < 256; k0 += 64) {
    int r = t >> 2, off = (t & 3) * 16;
    const unsigned short* ga = xnT + ((size_t)b * Cn + c0 + r) * Nn + nb + k0 + off;
    const unsigned short* gb = weT + (size_t)r * Nn + nb + k0 + off;
    #pragma unroll
    for (int i = 0; i < 2; i++) {
      *(us8v*)(lds + r * 128 + ((off * 2 + 16 * i) ^ ((r & 7) << 4))) = *(const us8v*)(ga + i * 8);
      *(us8v*)(lds + 8192 + r * 128 + ((off * 2 + 16 * i) ^ ((r & 7) << 4))) = *(const us8v*)(gb + i * 8);
    }
    __syncthreads();
    #pragma unroll
    for (int ks = 0; ks < 2; ks++) {
      int kb = ks * 64 + (lane >> 4) * 16;
      int rowa = wid * 16 + (lane & 15);
      bf16x8 a = *(bf16x8*)(lds + rowa * 128 + (kb ^ ((rowa & 7) << 4)));
      #pragma unroll
      for (int pt = 0; pt < 4; pt++) {
        int rowb = pt * 16 + (lane & 15);
        bf16x8 bv = *(bf16x8*)(lds + 8192 + rowb * 128 + (kb ^ ((rowb & 7) << 4)));
        acc4[pt] = __builtin_amdgcn_mfma_f32_16x16x32_bf16(a, bv, acc4[pt], 0, 0, 0);
      }
    }
    __syncthreads();
  }
  size_t base = ((size_t)(b * NCH + chunk)) * (Cn * Pn);
  #pragma unroll
  for (int pt = 0; pt < 4; pt++)
    #pragma unroll
    for (int e = 0; e < 4; e++) {
      int c = c0 + wid * 16 + (lane >> 4) * 4 + e;
      int p = pt * 16 + (lane & 15);
      part[base + (size_t)c * Pn + p] = acc4[pt][e];
    }
}

__global__ __launch_bounds__(256) void k_xe_reduce(const float* __restrict__ part,
                                                   float* __restrict__ xe) {
  int i = blockIdx.x * 256 + threadIdx.x;
  int b = i / (Cn * Pn);
  int cp = i % (Cn * Pn);
  float s = 0.f;
  for (int ch = 0; ch < NCH; ch++) s += part[(size_t)(b * NCH + ch) * Cn * Pn + cp];
  xe[i] = s;
}

// ---------------- kv proj (scale*T folded into k side) ----------------
__global__ __launch_bounds__(256) void k_kvproj(const float* __restrict__ xe,
                                                const float* __restrict__ wqkv,
                                                const float* __restrict__ be,
                                                const float* __restrict__ qsq,
                                                const float* __restrict__ temp,
                                                unsigned short* __restrict__ kvp) {
  int hd = blockIdx.x * 4 + (threadIdx.x >> 6);
  int kv = blockIdx.y, b = blockIdx.z;
  int p = threadIdx.x & 63;
  int col = (kv + 1) * Cn + hd;
  float acc = be[p];
  for (int c = 0; c < Cn; c++)
    acc = fmaf(xe[((size_t)b * Cn + c) * Pn + p], wqkv[(size_t)c * 768 + col], acc);
  int h = hd >> 6, d = hd & 63;
  if (kv == 0) {
    float sc = 1.f / fmaxf(sqrtf(qsq[b * Cn + hd]), 1e-12f);
    acc *= sc * temp[h];
    kvp[((size_t)(b * 4 + h)) * 4096 + p * 64 + d] = f2bf(acc);
  } else {
    kvp[32768 + ((size_t)(b * 4 + h)) * 4096 + d * 64 + p] = f2bf(acc);
  }
}

// ---------------- gate = sigmoid(relu(pooled @ wfc1) @ wfc2) ----------------
__global__ __launch_bounds__(256) void k_gate(const float* __restrict__ pooledacc,
                                              const float* __restrict__ bpool,
                                              const float* __restrict__ wfc1,
                                              const float* __restrict__ wfc2,
                                              float* __restrict__ gate) {
  int b = blockIdx.x, t = threadIdx.x;
  __shared__ float pl[256], h1[64];
  pl[t] = pooledacc[b * Cn + t] + bpool[0];
  __syncthreads();
  if (t < 64) {
    float a = 0.f;
    for (int c = 0; c < Cn; c++) a = fmaf(pl[c], wfc1[c * 64 + t], a);
    h1[t] = fmaxf(a, 0.f);
  }
  __syncthreads();
  float a = 0.f;
  for (int j = 0; j < 64; j++) a = fmaf(h1[j], wfc2[j * Cn + t], a);
  gate[b * Cn + t] = 1.f / (1.f + __expf(-a));
}

// ---------------- attention (bf16 MFMA, P=64, per-token softmax) -------------
__global__ __launch_bounds__(128) void k_attn(const unsigned short* __restrict__ qbf,
                                              const unsigned short* __restrict__ kvp,
                                              unsigned short* __restrict__ xsa) {
  __shared__ char lds[16384 + 2 * 9216];
  int nb = blockIdx.x, h = blockIdx.y, b = blockIdx.z;
  int t = threadIdx.x, lane = t & 63, w = t >> 6;
  char* kpT = lds;
  char* vp = lds + 8192;
  unsigned short* P = (unsigned short*)(lds + 16384 + w * 9216);
  const unsigned short* kg = kvp + ((size_t)(b * 4 + h)) * 4096;
  const unsigned short* vg = kvp + 32768 + ((size_t)(b * 4 + h)) * 4096;
  {
    int r = t >> 1, off = (t & 1) * 32;
    #pragma unroll
    for (int i = 0; i < 4; i++) {
      *(us8v*)(kpT + r * 128 + ((off * 2 + 16 * i) ^ ((r & 7) << 4))) = *(const us8v*)(kg + r * 64 + off + i * 8);
      *(us8v*)(vp + r * 128 + ((off * 2 + 16 * i) ^ ((r & 7) << 4))) = *(const us8v*)(vg + r * 64 + off + i * 8);
    }
  }
  __syncthreads();
  int n0 = nb * 128 + w * 64;
  bf16x8 qf[4][2];
  #pragma unroll
  for (int tt = 0; tt < 4; tt++)
    #pragma unroll
    for (int ks = 0; ks < 2; ks++) {
      int n = n0 + tt * 16 + (lane & 15);
      qf[tt][ks] = *(const bf16x8*)(qbf + ((size_t)b * Nn + n) * 256 + h * 64 + ks * 32 + (lane >> 4) * 8);
    }
  f32x4 s[4][4];
  #pragma unroll
  for (int i = 0; i < 4; i++)
    #pragma unroll
    for (int j = 0; j < 4; j++) s[i][j] = (f32x4){0.f, 0.f, 0.f, 0.f};
  #pragma unroll
  for (int ks = 0; ks < 2; ks++) {
    int kb = ks * 64 + (lane >> 4) * 16;
    #pragma unroll
    for (int mt = 0; mt < 4; mt++) {
      int row = mt * 16 + (lane & 15);
      bf16x8 a = *(bf16x8*)(kpT + row * 128 + (kb ^ ((row & 7) << 4)));
      #pragma unroll
      for (int tt = 0; tt < 4; tt++)
        s[mt][tt] = __builtin_amdgcn_mfma_f32_16x16x32_bf16(a, qf[tt][ks], s[mt][tt], 0, 0, 0);
    }
  }
  #pragma unroll
  for (int tt = 0; tt < 4; tt++) {
    float mx = -1e30f;
    #pragma unroll
    for (int mt = 0; mt < 4; mt++)
      #pragma unroll
      for (int e = 0; e < 4; e++) mx = fmaxf(mx, s[mt][tt][e]);
    mx = fmaxf(mx, __shfl_xor(mx, 16));
    mx = fmaxf(mx, __shfl_xor(mx, 32));
    float den = 0.f;
    #pragma unroll
    for (int mt = 0; mt < 4; mt++)
      #pragma unroll
      for (int e = 0; e < 4; e++) {
        float ev = __expf(s[mt][tt][e] - mx);
        s[mt][tt][e] = ev; den += ev;
      }
    den += __shfl_xor(den, 16);
    den += __shfl_xor(den, 32);
    float inv = 1.f / den;
    #pragma unroll
    for (int mt = 0; mt < 4; mt++)
      #pragma unroll
      for (int e = 0; e < 4; e++) s[mt][tt][e] *= inv;
  }
  #pragma unroll
  for (int mt = 0; mt < 4; mt++)
    #pragma unroll
    for (int tt = 0; tt < 4; tt++) {
      int tok = tt * 16 + (lane & 15);
      int pb = mt * 16 + ((lane >> 4) << 2);
      uint2 v;
      v.x = pk2(s[mt][tt][0], s[mt][tt][1]);
      v.y = pk2(s[mt][tt][2], s[mt][tt][3]);
      *(uint2*)(P + tok * 72 + pb) = v;
    }
  bf16x8 pf[4][2];
  #pragma unroll
  for (int mt = 0; mt < 4; mt++)
    #pragma unroll
    for (int ks = 0; ks < 2; ks++)
      pf[mt][ks] = *(const bf16x8*)(P + (mt * 16 + (lane & 15)) * 72 + ks * 32 + (lane >> 4) * 8);
  f32x4 o[4][4];
  #pragma unroll
  for (int i = 0; i < 4; i++)
    #pragma unroll
    for (int j = 0; j < 4; j++) o[i][j] = (f32x4){0.f, 0.f, 0.f, 0.f};
  #pragma unroll
  for (int ks = 0; ks < 2; ks++) {
    int kb = ks * 64 + (lane >> 4) * 16;
    #pragma unroll
    for (int nt = 0; nt < 4; nt++) {
      int row = nt * 16 + (lane & 15);
      bf16x8 bfv = *(bf16x8*)(vp + row * 128 + (kb ^ ((row & 7) << 4)));
      #pragma unroll
      for (int mt = 0; mt < 4; mt++)
        o[mt][nt] = __builtin_amdgcn_mfma_f32_16x16x32_bf16(pf[mt][ks], bfv, o[mt][nt], 0, 0, 0);
    }
  }
  #pragma unroll
  for (int mt = 0; mt < 4; mt++)
    #pragma unroll
    for (int nt = 0; nt < 4; nt++) {
      int d = nt * 16 + (lane & 15);
      int tb = mt * 16 + ((lane >> 4) << 2);
      uint2 v;
      v.x = pk2(o[mt][nt][0], o[mt][nt][1]);
      v.y = pk2(o[mt][nt][2], o[mt][nt][3]);
      *(uint2*)(P + d * 72 + tb) = v;
    }
  size_t fb = (size_t)b * Cn * Nn + ((size_t)(lane * 4 + h)) * Nn + n0;
  #pragma unroll
  for (int k = 0; k < 8; k++)
    *(us8v*)(xsa + fb + k * 8) = *(const us8v*)(P + lane * 72 + k * 8);
}

// ---------------- out GEMM (bf16 MFMA) + fused epilogue ----------------
template <int GATE>
__global__ __launch_bounds__(256) void k_gemm_out(
    const unsigned short* __restrict__ Aw,
    const unsigned short* __restrict__ Bx,
    const float* __restrict__ bias, int cbase,
    const unsigned short* __restrict__ xnT, const float* __restrict__ gamma,
    const float* __restrict__ gate,
    float* __restrict__ outp) {
  __shared__ char lds[34816];
  int b = blockIdx.z, n0 = blockIdx.x * 128, j0 = blockIdx.y * 64;
  int t = threadIdx.x, lane = t & 63, wid = t >> 6;
  int wj = wid >> 1, wt = wid & 1;
  float* gs = (float*)(lds + 33792);
  if (GATE) { gs[t] = gate[b * Cn + t]; }
  __syncthreads();
  f32x4 acc[2][4];
  #pragma unroll
  for (int i = 0; i < 2; i++)
    #pragma unroll
    for (int j = 0; j < 4; j++) acc[i][j] = (f32x4){0.f, 0.f, 0.f, 0.f};
  for (int k0 = 0; k0 < 256; k0 += 64) {
    {
      int r = t >> 2, off = (t & 3) * 16;
      const unsigned short* ga = Aw + (size_t)(j0 + r) * 256 + k0 + off;
      #pragma unroll
      for (int i = 0; i < 2; i++) {
        us8v v = *(const us8v*)(ga + i * 8);
        if (GATE) {
          #pragma unroll
          for (int e = 0; e < 8; e++) v[e] = f2bf(bf2f(v[e]) * gs[k0 + off + i * 8 + e]);
        }
        *(us8v*)(lds + r * 128 + ((off * 2 + 16 * i) ^ ((r & 7) << 4))) = v;
      }
      int rb = t >> 1, offb = (t & 1) * 32;
      const unsigned short* gbp = Bx + ((size_t)b * Nn + n0 + rb) * 256 + k0 + offb;
      #pragma unroll
      for (int i = 0; i < 4; i++)
        *(us8v*)(lds + 8192 + rb * 128 + ((offb * 2 + 16 * i) ^ ((rb & 7) << 4))) = *(const us8v*)(gbp + i * 8);
    }
    __syncthreads();
    #pragma unroll
    for (int ks = 0; ks < 2; ks++) {
      int kb = ks * 64 + (lane >> 4) * 16;
      bf16x8 af[2], bfr[4];
      #pragma unroll
      for (int mt = 0; mt < 2; mt++) {
        int row = wj * 32 + mt * 16 + (lane & 15);
        af[mt] = *(bf16x8*)(lds + row * 128 + (kb ^ ((row & 7) << 4)));
      }
      #pragma unroll
      for (int tt = 0; tt < 4; tt++) {
        int row = wt * 64 + tt * 16 + (lane & 15);
        bfr[tt] = *(bf16x8*)(lds + 8192 + row * 128 + (kb ^ ((row & 7) << 4)));
      }
      #pragma unroll
      for (int mt = 0; mt < 2; mt++)
        #pragma unroll
        for (int tt = 0; tt < 4; tt++)
          acc[mt][tt] = __builtin_amdgcn_mfma_f32_16x16x32_bf16(af[mt], bfr[tt], acc[mt][tt], 0, 0, 0);
    }
    __syncthreads();
  }
  float* OT = (float*)lds;  // [64 j][132 tok]
  #pragma unroll
  for (int mt = 0; mt < 2; mt++)
    #pragma unroll
    for (int tt = 0; tt < 4; tt++)
      #pragma unroll
      for (int e = 0; e < 4; e++) {
        int j = wj * 32 + mt * 16 + (lane >> 4) * 4 + e;
        int tok = wt * 64 + tt * 16 + (lane & 15);
        OT[j * 132 + tok] = acc[mt][tt][e];
      }
  __syncthreads();
  int jj = t >> 2, ts = (t & 3) * 32;
  int c = cbase + j0 + jj;
  float gm = gamma[c], bi = bias[j0 + jj];
  const unsigned short* xn = xnT + ((size_t)b * Cn + c) * Nn + n0 + ts;
  float* op = outp + ((size_t)b * Cn + c) * Nn + n0 + ts;
  #pragma unroll
  for (int i = 0; i < 8; i++) {
    f32x4 v = *(const f32x4*)(&OT[jj * 132 + ts + i * 4]);
    us4v xv = *(const us4v*)(xn + i * 4);
    f32x4 ov;
    #pragma unroll
    for (int e = 0; e < 4; e++) ov[e] = bf2f(xv[e]) + gm * (v[e] + bi);
    *(f32x4*)(op + i * 4) = ov;
  }
}

extern "C" void kernel_launch(void* const* d_in, const int* in_sizes, int n_in,
                              void* d_out, int out_size, void* d_ws, size_t ws_size,
                              hipStream_t stream) {
  const float* x      = (const float*)d_in[0];
  const float* pos    = (const float*)d_in[1];
  const float* ln_g   = (const float*)d_in[2];
  const float* ln_b   = (const float*)d_in[3];
  const float* gamma  = (const float*)d_in[4];
  const float* temp2  = (const float*)d_in[5];
  const float* w_qkv  = (const float*)d_in[6];
  const float* w_e    = (const float*)d_in[7];
  const float* b_e    = (const float*)d_in[8];
  const float* w_pool = (const float*)d_in[9];
  const float* b_pool = (const float*)d_in[10];
  const float* w_fc1  = (const float*)d_in[11];
  const float* w_fc2  = (const float*)d_in[12];
  const float* w_out1 = (const float*)d_in[13];
  const float* b_out1 = (const float*)d_in[14];
  const float* w_out2 = (const float*)d_in[15];
  const float* b_out2 = (const float*)d_in[16];
  const float* w_c1   = (const float*)d_in[17];
  const float* b_c1   = (const float*)d_in[18];
  const float* w_c2   = (const float*)d_in[19];
  const float* b_c2   = (const float*)d_in[20];
  (void)in_sizes; (void)n_in; (void)out_size; (void)ws_size;
  float* out = (float*)d_out;

  const size_t SZ = (size_t)Bn * Cn * Nn;   // 7,077,888 elements
  char* base = (char*)d_ws;
  size_t off = 0;
  auto alloc = [&](size_t bytes) { void* p = base + off; off += (bytes + 255) & ~(size_t)255; return p; };
  unsigned short* xTbf  = (unsigned short*)alloc(SZ * 2);
  unsigned short* t1T   = (unsigned short*)alloc(SZ * 2);  // reused as qbf
  unsigned short* t3T   = (unsigned short*)alloc(SZ * 2);
  unsigned short* xnbf  = (unsigned short*)alloc(SZ * 2);
  unsigned short* xcnbf = (unsigned short*)alloc(SZ * 2);
  unsigned short* xnTbf = (unsigned short*)alloc(SZ * 2);
  unsigned short* xsabf = (unsigned short*)alloc(SZ * 2);
  unsigned short* W1e   = (unsigned short*)alloc(65536 * 2);
  unsigned short* W2e   = (unsigned short*)alloc(65536 * 2);
  unsigned short* wqkvT = (unsigned short*)alloc((size_t)768 * 256 * 2);
  unsigned short* w1T   = (unsigned short*)alloc(32768 * 2);
  unsigned short* w2T   = (unsigned short*)alloc(32768 * 2);
  unsigned short* weT   = (unsigned short*)alloc((size_t)Pn * Nn * 2);
  float* xepart = (float*)alloc((size_t)NCH * Bn * Cn * Pn * 4);
  float* zeros  = (float*)alloc(3072 * 4);
  float* stats1acc = zeros;            // 1024
  float* stats3acc = zeros + 1024;     // 1024
  float* qsq       = zeros + 2048;     // 512
  float* pooledacc = zeros + 2560;     // 512
  float* stats1 = (float*)alloc(1024 * 4);
  float* stats3 = (float*)alloc(1024 * 4);
  float* xe     = (float*)alloc(32768 * 4);
  float* gateb  = (float*)alloc(512 * 4);
  unsigned short* kvp = (unsigned short*)alloc(65536 * 2);
  unsigned short* qbf = t1T;

  k_prep<<<dim3(2521), 256, 0, stream>>>(x, w_qkv, w_e, w_out1, w_out2, w_c1, w_c2,
                                         xTbf, W1e, W2e, wqkvT, w1T, w2T, weT, zeros);
  k_mm<0><<<dim3(108, 2, Bn), 256, 0, stream>>>(W1e, xTbf, b_c1, nullptr, t1T, stats1acc);
  k_statfin<<<dim3(2), 256, 0, stream>>>(stats1acc, stats1);
  k_mm<1><<<dim3(108, 2, Bn), 256, 0, stream>>>(W2e, t1T, b_c2, stats1, t3T, stats3acc);
  k_statfin<<<dim3(2), 256, 0, stream>>>(stats3acc, stats3);
  k_fused_ln<<<dim3(432, Bn), 256, 0, stream>>>(xTbf, t3T, pos, stats3, ln_g, ln_b,
                                                w_pool, xnbf, xcnbf, pooledacc);
  k_mm<2><<<dim3(108, 2, Bn), 256, 0, stream>>>(wqkvT, xnbf, nullptr, nullptr, qbf, qsq);
  k_xpose<<<dim3(216, 4, Bn), 256, 0, stream>>>(xnbf, xnTbf);
  k_xe<<<dim3(NCH, 4, Bn), 256, 0, stream>>>(xnTbf, weT, xepart);
  k_xe_reduce<<<dim3(128), 256, 0, stream>>>(xepart, xe);
  k_kvproj<<<dim3(64, 2, Bn), 256, 0, stream>>>(xe, w_qkv, b_e, qsq, temp2, kvp);
  k_gate<<<dim3(Bn), 256, 0, stream>>>(pooledacc, b_pool, w_fc1, w_fc2, gateb);
  k_attn<<<dim3(108, NHn, Bn), 128, 0, stream>>>(qbf, kvp, xsabf);
  k_gemm_out<0><<<dim3(108, 2, Bn), 256, 0, stream>>>(w1T, xsabf, b_out1, 0, xnTbf, gamma, nullptr, out);
  k_gemm_out<1><<<dim3(108, 2, Bn), 256, 0, stream>>>(w2T, xcnbf, b_out2, 128, xnTbf, gamma, gateb, out);
}